// Round 6
// baseline (57.859 us; speedup 1.0000x reference)
//
#include <hip/hip_runtime.h>

#define EPSF 1e-8f
#define PROB_PENALTYF 1e-4f
#define REV_SCALEF 0.1f

#define BLK 256
#define P 8               // points per thread in min_kernel
#define TILE 160          // divides 16000 (fwd sources) and 8000 (rev sources)
#define INFBITS 0x7F800000u

__device__ __forceinline__ float min3f(float a, float b, float c) {
    return fminf(fminf(a, b), c);   // -> v_min3_f32
}

// ---------------- kernel 0: prep ----------------
// Precomputes once:
//   obc4   [f_orig]: original barycenters   {x,y,z,|.|^2}   (fwd sources)
//   overts4[n_orig]: original vertices      {x,y,z,|.|^2}   (rev sources)
//   fwdPts [fs]    : simplified barycenters {-2x,-2y,-2z,|.|^2}
//   revPts [npts]  : sampled points         {-2x,-2y,-2z,|.|^2}
// and initializes fwd_min/rev_min to +inf bits, acc[0..7] = 0.
__global__ void prep_kernel(const float* __restrict__ overts,
                            const int* __restrict__ ofaces,
                            const float* __restrict__ sverts,
                            const int* __restrict__ sfaces,
                            const float* __restrict__ u1,
                            const float* __restrict__ u2,
                            float4* __restrict__ obc4,
                            float4* __restrict__ overts4,
                            float4* __restrict__ fwdPts,
                            float4* __restrict__ revPts,
                            unsigned int* __restrict__ fwd_min,
                            unsigned int* __restrict__ rev_min,
                            float* __restrict__ acc,
                            int n_orig, int f_orig, int fs, int S, int npts) {
    int i = blockIdx.x * blockDim.x + threadIdx.x;
    const float third = 1.0f / 3.0f;
    if (i < 8) acc[i] = 0.0f;
    if (i < npts) {
        rev_min[i] = INFBITS;
        int f = i / S;
        float r1 = sqrtf(u1[i]);
        float uu2 = u2[i];
        float wa = 1.0f - r1;
        float wb = r1 * (1.0f - uu2);
        float wc = r1 * uu2;
        int a = sfaces[3 * f], b = sfaces[3 * f + 1], c = sfaces[3 * f + 2];
        float x = wa * sverts[3 * a] + wb * sverts[3 * b] + wc * sverts[3 * c];
        float y = wa * sverts[3 * a + 1] + wb * sverts[3 * b + 1] + wc * sverts[3 * c + 1];
        float z = wa * sverts[3 * a + 2] + wb * sverts[3 * b + 2] + wc * sverts[3 * c + 2];
        revPts[i] = make_float4(-2.0f * x, -2.0f * y, -2.0f * z, x * x + y * y + z * z);
    }
    if (i < fs) {
        fwd_min[i] = INFBITS;
        int a = sfaces[3 * i], b = sfaces[3 * i + 1], c = sfaces[3 * i + 2];
        float x = (sverts[3 * a] + sverts[3 * b] + sverts[3 * c]) * third;
        float y = (sverts[3 * a + 1] + sverts[3 * b + 1] + sverts[3 * c + 1]) * third;
        float z = (sverts[3 * a + 2] + sverts[3 * b + 2] + sverts[3 * c + 2]) * third;
        fwdPts[i] = make_float4(-2.0f * x, -2.0f * y, -2.0f * z, x * x + y * y + z * z);
    }
    if (i < f_orig) {
        int a = ofaces[3 * i], b = ofaces[3 * i + 1], c = ofaces[3 * i + 2];
        float x = (overts[3 * a] + overts[3 * b] + overts[3 * c]) * third;
        float y = (overts[3 * a + 1] + overts[3 * b + 1] + overts[3 * c + 1]) * third;
        float z = (overts[3 * a + 2] + overts[3 * b + 2] + overts[3 * c + 2]) * third;
        obc4[i] = make_float4(x, y, z, x * x + y * y + z * z);
    }
    if (i < n_orig) {
        float x = overts[3 * i], y = overts[3 * i + 1], z = overts[3 * i + 2];
        overts4[i] = make_float4(x, y, z, x * x + y * y + z * z);
    }
}

// ---------------- kernel 1: fused fwd+rev min-distance, NO LDS ----------------
// blocks [0, fwdBlocks): fwd (fwdPts vs obc4); rest: rev (revPts vs overts4).
// Sources are read with wave-UNIFORM addresses (compile-time j offsets from a
// block-uniform base) -> compiler emits s_load batches on the scalar pipe; the
// inner loop is pure VALU (3 fma + amortized min3 per pair). Each thread owns
// P points (coalesced b128 loads); per-point min merged across tile-blocks via
// atomicMin on float bits (values >= 0; arrays pre-set to +inf bits).
__global__ void __launch_bounds__(BLK)
min_kernel(const float4* __restrict__ fwdPts,
           const float4* __restrict__ revPts,
           const float4* __restrict__ obc4,
           const float4* __restrict__ overts4,
           unsigned int* __restrict__ fwd_min,
           unsigned int* __restrict__ rev_min,
           int fwdBlocks, int fwdPtBlocks, int f_orig, int fs,
           int revPtBlocks, int n_orig, int npts_rev) {
    int bid = blockIdx.x;
    int t = threadIdx.x;

    bool isFwd = (bid < fwdBlocks);
    const float4* pts;
    const float4* src;
    unsigned int* outmin;
    int nsrc, npts, pb, cb;
    if (isFwd) {
        pts = fwdPts; src = obc4; outmin = fwd_min; nsrc = f_orig; npts = fs;
        pb = bid % fwdPtBlocks; cb = bid / fwdPtBlocks;
    } else {
        int b = bid - fwdBlocks;
        pts = revPts; src = overts4; outmin = rev_min; nsrc = n_orig; npts = npts_rev;
        pb = b % revPtBlocks; cb = b / revPtBlocks;
    }

    // ---- per-thread points (coalesced, clamped) ----
    int pbase = pb * BLK * P;
    float pa[P], pbv[P], pc[P], m[P];
    #pragma unroll
    for (int i = 0; i < P; ++i) {
        int k = pbase + i * BLK + t;
        k = min(k, npts - 1);
        float4 q = pts[k];
        pa[i] = q.x; pbv[i] = q.y; pc[i] = q.z;
        m[i] = __uint_as_float(INFBITS);
    }

    int base = cb * TILE;
    if (base + TILE <= nsrc) {
        // ---- fast path: full tile, constant trip, uniform scalar loads ----
        const float4* s = src + base;
        for (int j = 0; j < TILE; j += 8) {
            float4 v0 = s[j + 0];
            float4 v1 = s[j + 1];
            float4 v2 = s[j + 2];
            float4 v3 = s[j + 3];
            float4 v4 = s[j + 4];
            float4 v5 = s[j + 5];
            float4 v6 = s[j + 6];
            float4 v7 = s[j + 7];
            #pragma unroll
            for (int i = 0; i < P; ++i) {
                float a = pa[i], b = pbv[i], c = pc[i];
                float s0 = fmaf(c, v0.z, fmaf(b, v0.y, fmaf(a, v0.x, v0.w)));
                float s1 = fmaf(c, v1.z, fmaf(b, v1.y, fmaf(a, v1.x, v1.w)));
                float s2 = fmaf(c, v2.z, fmaf(b, v2.y, fmaf(a, v2.x, v2.w)));
                float s3 = fmaf(c, v3.z, fmaf(b, v3.y, fmaf(a, v3.x, v3.w)));
                float s4 = fmaf(c, v4.z, fmaf(b, v4.y, fmaf(a, v4.x, v4.w)));
                float s5 = fmaf(c, v5.z, fmaf(b, v5.y, fmaf(a, v5.x, v5.w)));
                float s6 = fmaf(c, v6.z, fmaf(b, v6.y, fmaf(a, v6.x, v6.w)));
                float s7 = fmaf(c, v7.z, fmaf(b, v7.y, fmaf(a, v7.x, v7.w)));
                float q = m[i];
                q = min3f(q, s0, s1);
                q = min3f(q, s2, s3);
                q = min3f(q, s4, s5);
                q = min3f(q, s6, s7);
                m[i] = q;
            }
        }
    } else {
        // ---- tail path: clamp source index (duplicate mins are harmless) ----
        for (int j = 0; j < TILE; ++j) {
            int g = min(base + j, nsrc - 1);
            float4 v = src[g];
            #pragma unroll
            for (int i = 0; i < P; ++i) {
                float s0 = fmaf(pc[i], v.z, fmaf(pbv[i], v.y, fmaf(pa[i], v.x, v.w)));
                m[i] = fminf(m[i], s0);
            }
        }
    }

    // ---- write back: d2 = |p|^2 + min(|v|^2 - 2 p.v), clamped >= 0 ----
    #pragma unroll
    for (int i = 0; i < P; ++i) {
        int k = pbase + i * BLK + t;
        if (k < npts) {
            float p2 = pts[k].w;
            float d2 = fmaxf(p2 + m[i], 0.0f);
            atomicMin(&outmin[k], __float_as_uint(d2));
        }
    }
}

// ---------------- kernel 2: reductions + final scalar (last-block writes out) ----------------
__global__ void finalize_kernel(const unsigned int* __restrict__ fwd_min,
                                const unsigned int* __restrict__ rev_min,
                                const float* __restrict__ fp,
                                float* acc, float* out,
                                int fs, int npts, int S, int nblocks) {
    __shared__ float s1[BLK], s2[BLK], s3[BLK];
    int k = blockIdx.x * blockDim.x + threadIdx.x;
    float fsum = 0.f, rsum = 0.f, rmax = 0.f;
    if (k < npts) {
        float md = __uint_as_float(rev_min[k]);
        float p = fp[k / S];
        rsum = p * md;
        rmax = md;
    }
    if (k < fs) {
        float p = fp[k];
        fsum = p * __uint_as_float(fwd_min[k]) + PROB_PENALTYF * (1.0f - p);
    }
    s1[threadIdx.x] = fsum;
    s2[threadIdx.x] = rsum;
    s3[threadIdx.x] = rmax;
    __syncthreads();
    for (int off = BLK / 2; off > 0; off >>= 1) {
        if ((int)threadIdx.x < off) {
            s1[threadIdx.x] += s1[threadIdx.x + off];
            s2[threadIdx.x] += s2[threadIdx.x + off];
            s3[threadIdx.x] = fmaxf(s3[threadIdx.x], s3[threadIdx.x + off]);
        }
        __syncthreads();
    }
    if (threadIdx.x == 0) {
        atomicAdd(&acc[0], s1[0]);
        atomicAdd(&acc[1], s2[0]);
        atomicMax((unsigned int*)&acc[2], __float_as_uint(s3[0]));
        __threadfence();
        unsigned int ticket = atomicAdd((unsigned int*)&acc[3], 1u);
        if (ticket == (unsigned int)(nblocks - 1)) {
            __threadfence();
            float a0 = atomicAdd(&acc[0], 0.0f);
            float a1 = atomicAdd(&acc[1], 0.0f);
            unsigned int mb = atomicOr((unsigned int*)&acc[2], 0u);
            out[0] = a0 + a1 * (REV_SCALEF / (__uint_as_float(mb) + EPSF));
        }
    }
}

extern "C" void kernel_launch(void* const* d_in, const int* in_sizes, int n_in,
                              void* d_out, int out_size, void* d_ws, size_t ws_size,
                              hipStream_t stream) {
    const float* overts = (const float*)d_in[0];
    const int*   ofaces = (const int*)d_in[1];
    const float* sverts = (const float*)d_in[2];
    const int*   sfaces = (const int*)d_in[3];
    const float* fp     = (const float*)d_in[4];
    const float* u1     = (const float*)d_in[5];
    const float* u2     = (const float*)d_in[6];
    float* out = (float*)d_out;

    const int N_ORIG = in_sizes[0] / 3;
    const int F_ORIG = in_sizes[1] / 3;
    const int F_SIMP = in_sizes[3] / 3;
    const int S      = in_sizes[5] / F_SIMP;
    const int NPTS   = F_SIMP * S;

    // workspace: obc4 | overts4 | fwdPts | revPts | fwd_min | rev_min | acc
    float4* obc4    = (float4*)d_ws;
    float4* overts4 = obc4 + F_ORIG;
    float4* fwdPts  = overts4 + N_ORIG;
    float4* revPts  = fwdPts + F_SIMP;
    unsigned int* fwd_min = (unsigned int*)(revPts + NPTS);
    unsigned int* rev_min = fwd_min + F_SIMP;
    float* acc = (float*)(rev_min + NPTS);

    int prepN = max(max(NPTS, F_ORIG), N_ORIG);
    hipLaunchKernelGGL(prep_kernel, dim3((prepN + BLK - 1) / BLK), dim3(BLK), 0, stream,
                       overts, ofaces, sverts, sfaces, u1, u2,
                       obc4, overts4, fwdPts, revPts, fwd_min, rev_min, acc,
                       N_ORIG, F_ORIG, F_SIMP, S, NPTS);

    // fwd: 2 point-blocks x 100 tiles = 200; rev: 16 point-blocks x 50 tiles = 800
    const int fwdPtBlocks = (F_SIMP + BLK * P - 1) / (BLK * P);
    const int fwdTiles    = (F_ORIG + TILE - 1) / TILE;
    const int fwdBlocks   = fwdPtBlocks * fwdTiles;

    const int revPtBlocks = (NPTS + BLK * P - 1) / (BLK * P);
    const int revTiles    = (N_ORIG + TILE - 1) / TILE;
    const int revBlocks   = revPtBlocks * revTiles;

    hipLaunchKernelGGL(min_kernel, dim3(fwdBlocks + revBlocks), dim3(BLK), 0, stream,
                       fwdPts, revPts, obc4, overts4, fwd_min, rev_min,
                       fwdBlocks, fwdPtBlocks, F_ORIG, F_SIMP,
                       revPtBlocks, N_ORIG, NPTS);

    const int finBlocks = (NPTS + BLK - 1) / BLK;
    hipLaunchKernelGGL(finalize_kernel, dim3(finBlocks), dim3(BLK), 0, stream,
                       fwd_min, rev_min, fp, acc, out, F_SIMP, NPTS, S, finBlocks);
}

// Round 7
// 44.525 us; speedup vs baseline: 1.2995x; 1.2995x over previous
//
#include <hip/hip_runtime.h>

#define EPSF 1e-8f
#define PROB_PENALTYF 1e-4f
#define REV_SCALEF 0.1f

#define BLK 1024          // 16 waves/block -> fills wave slots
#define P 4               // points per thread in min_kernel
#define TILE 160          // divides 16000 (fwd sources) and 8000 (rev sources)
#define FBLK 256          // block size for prep/finalize
#define INFBITS 0x7F800000u

// sentinel "far away" source (only used if nsrc % TILE != 0)
#define SENT_C 1.0e6f
#define SENT_W 3.0e12f

__device__ __forceinline__ float min3f(float a, float b, float c) {
    return fminf(fminf(a, b), c);   // -> v_min3_f32
}

// ---------------- kernel 0: prep ----------------
// Precomputes once:
//   obc4   [f_orig]: original barycenters   {x,y,z,|.|^2}   (fwd sources)
//   overts4[n_orig]: original vertices      {x,y,z,|.|^2}   (rev sources)
//   fwdPts [fs]    : simplified barycenters {-2x,-2y,-2z,|.|^2}
//   revPts [npts]  : sampled points         {-2x,-2y,-2z,|.|^2}
// and initializes fwd_min/rev_min to +inf bits, acc[0..7] = 0.
__global__ void prep_kernel(const float* __restrict__ overts,
                            const int* __restrict__ ofaces,
                            const float* __restrict__ sverts,
                            const int* __restrict__ sfaces,
                            const float* __restrict__ u1,
                            const float* __restrict__ u2,
                            float4* __restrict__ obc4,
                            float4* __restrict__ overts4,
                            float4* __restrict__ fwdPts,
                            float4* __restrict__ revPts,
                            unsigned int* __restrict__ fwd_min,
                            unsigned int* __restrict__ rev_min,
                            float* __restrict__ acc,
                            int n_orig, int f_orig, int fs, int S, int npts) {
    int i = blockIdx.x * blockDim.x + threadIdx.x;
    const float third = 1.0f / 3.0f;
    if (i < 8) acc[i] = 0.0f;
    if (i < npts) {
        rev_min[i] = INFBITS;
        int f = i / S;
        float r1 = sqrtf(u1[i]);
        float uu2 = u2[i];
        float wa = 1.0f - r1;
        float wb = r1 * (1.0f - uu2);
        float wc = r1 * uu2;
        int a = sfaces[3 * f], b = sfaces[3 * f + 1], c = sfaces[3 * f + 2];
        float x = wa * sverts[3 * a] + wb * sverts[3 * b] + wc * sverts[3 * c];
        float y = wa * sverts[3 * a + 1] + wb * sverts[3 * b + 1] + wc * sverts[3 * c + 1];
        float z = wa * sverts[3 * a + 2] + wb * sverts[3 * b + 2] + wc * sverts[3 * c + 2];
        revPts[i] = make_float4(-2.0f * x, -2.0f * y, -2.0f * z, x * x + y * y + z * z);
    }
    if (i < fs) {
        fwd_min[i] = INFBITS;
        int a = sfaces[3 * i], b = sfaces[3 * i + 1], c = sfaces[3 * i + 2];
        float x = (sverts[3 * a] + sverts[3 * b] + sverts[3 * c]) * third;
        float y = (sverts[3 * a + 1] + sverts[3 * b + 1] + sverts[3 * c + 1]) * third;
        float z = (sverts[3 * a + 2] + sverts[3 * b + 2] + sverts[3 * c + 2]) * third;
        fwdPts[i] = make_float4(-2.0f * x, -2.0f * y, -2.0f * z, x * x + y * y + z * z);
    }
    if (i < f_orig) {
        int a = ofaces[3 * i], b = ofaces[3 * i + 1], c = ofaces[3 * i + 2];
        float x = (overts[3 * a] + overts[3 * b] + overts[3 * c]) * third;
        float y = (overts[3 * a + 1] + overts[3 * b + 1] + overts[3 * c + 1]) * third;
        float z = (overts[3 * a + 2] + overts[3 * b + 2] + overts[3 * c + 2]) * third;
        obc4[i] = make_float4(x, y, z, x * x + y * y + z * z);
    }
    if (i < n_orig) {
        float x = overts[3 * i], y = overts[3 * i + 1], z = overts[3 * i + 2];
        overts4[i] = make_float4(x, y, z, x * x + y * y + z * z);
    }
}

// ---------------- kernel 1: fused fwd+rev min-distance ----------------
// blocks [0, fwdBlocks): fwd (fwdPts vs obc4); rest: rev (revPts vs overts4).
// One TILE of sources per block staged in LDS (single barrier); 1024 threads =
// 16 waves per block so the 500-block grid carries ~8000 waves (latency hiding).
// Each thread owns P points; per-point min merged across tile-blocks via
// atomicMin on float bits (values >= 0; arrays pre-set to +inf bits).
__global__ void __launch_bounds__(BLK, 6)
min_kernel(const float4* __restrict__ fwdPts,
           const float4* __restrict__ revPts,
           const float4* __restrict__ obc4,
           const float4* __restrict__ overts4,
           unsigned int* __restrict__ fwd_min,
           unsigned int* __restrict__ rev_min,
           int fwdBlocks, int fwdPtBlocks, int f_orig, int fs,
           int revPtBlocks, int n_orig, int npts_rev) {
    __shared__ float4 tile[TILE];
    int bid = blockIdx.x;
    int t = threadIdx.x;

    bool isFwd = (bid < fwdBlocks);
    const float4* pts;
    const float4* src;
    unsigned int* outmin;
    int nsrc, npts, pb, cb;
    if (isFwd) {
        pts = fwdPts; src = obc4; outmin = fwd_min; nsrc = f_orig; npts = fs;
        pb = bid % fwdPtBlocks; cb = bid / fwdPtBlocks;
    } else {
        int b = bid - fwdBlocks;
        pts = revPts; src = overts4; outmin = rev_min; nsrc = n_orig; npts = npts_rev;
        pb = b % revPtBlocks; cb = b / revPtBlocks;
    }

    // ---- stage one tile of sources ----
    if (t < TILE) {
        int g = cb * TILE + t;
        tile[t] = (g < nsrc) ? src[g] : make_float4(SENT_C, SENT_C, SENT_C, SENT_W);
    }

    // ---- per-thread points (coalesced, clamped) ----
    int pbase = pb * BLK * P;
    float pa[P], pbv[P], pc[P], m[P];
    #pragma unroll
    for (int i = 0; i < P; ++i) {
        int k = pbase + i * BLK + t;
        k = min(k, npts - 1);
        float4 q = pts[k];
        pa[i] = q.x; pbv[i] = q.y; pc[i] = q.z;
        m[i] = __uint_as_float(INFBITS);
    }

    __syncthreads();

    // ---- constant-trip inner loop: TILE/4 iterations, 4 sources each ----
    for (int j = 0; j < TILE; j += 4) {
        float4 v0 = tile[j + 0];
        float4 v1 = tile[j + 1];
        float4 v2 = tile[j + 2];
        float4 v3 = tile[j + 3];
        #pragma unroll
        for (int i = 0; i < P; ++i) {
            float a = pa[i], b = pbv[i], c = pc[i];
            float s0 = fmaf(c, v0.z, fmaf(b, v0.y, fmaf(a, v0.x, v0.w)));
            float s1 = fmaf(c, v1.z, fmaf(b, v1.y, fmaf(a, v1.x, v1.w)));
            float s2 = fmaf(c, v2.z, fmaf(b, v2.y, fmaf(a, v2.x, v2.w)));
            float s3 = fmaf(c, v3.z, fmaf(b, v3.y, fmaf(a, v3.x, v3.w)));
            m[i] = min3f(min3f(m[i], s0, s1), s2, s3);
        }
    }

    // ---- write back: d2 = |p|^2 + min(|v|^2 - 2 p.v), clamped >= 0 ----
    #pragma unroll
    for (int i = 0; i < P; ++i) {
        int k = pbase + i * BLK + t;
        if (k < npts) {
            float p2 = pts[k].w;
            float d2 = fmaxf(p2 + m[i], 0.0f);
            atomicMin(&outmin[k], __float_as_uint(d2));
        }
    }
}

// ---------------- kernel 2: reductions + final scalar (last-block writes out) ----------------
__global__ void finalize_kernel(const unsigned int* __restrict__ fwd_min,
                                const unsigned int* __restrict__ rev_min,
                                const float* __restrict__ fp,
                                float* acc, float* out,
                                int fs, int npts, int S, int nblocks) {
    __shared__ float s1[FBLK], s2[FBLK], s3[FBLK];
    int k = blockIdx.x * blockDim.x + threadIdx.x;
    float fsum = 0.f, rsum = 0.f, rmax = 0.f;
    if (k < npts) {
        float md = __uint_as_float(rev_min[k]);
        float p = fp[k / S];
        rsum = p * md;
        rmax = md;
    }
    if (k < fs) {
        float p = fp[k];
        fsum = p * __uint_as_float(fwd_min[k]) + PROB_PENALTYF * (1.0f - p);
    }
    s1[threadIdx.x] = fsum;
    s2[threadIdx.x] = rsum;
    s3[threadIdx.x] = rmax;
    __syncthreads();
    for (int off = FBLK / 2; off > 0; off >>= 1) {
        if ((int)threadIdx.x < off) {
            s1[threadIdx.x] += s1[threadIdx.x + off];
            s2[threadIdx.x] += s2[threadIdx.x + off];
            s3[threadIdx.x] = fmaxf(s3[threadIdx.x], s3[threadIdx.x + off]);
        }
        __syncthreads();
    }
    if (threadIdx.x == 0) {
        atomicAdd(&acc[0], s1[0]);
        atomicAdd(&acc[1], s2[0]);
        atomicMax((unsigned int*)&acc[2], __float_as_uint(s3[0]));
        __threadfence();
        unsigned int ticket = atomicAdd((unsigned int*)&acc[3], 1u);
        if (ticket == (unsigned int)(nblocks - 1)) {
            __threadfence();
            float a0 = atomicAdd(&acc[0], 0.0f);
            float a1 = atomicAdd(&acc[1], 0.0f);
            unsigned int mb = atomicOr((unsigned int*)&acc[2], 0u);
            out[0] = a0 + a1 * (REV_SCALEF / (__uint_as_float(mb) + EPSF));
        }
    }
}

extern "C" void kernel_launch(void* const* d_in, const int* in_sizes, int n_in,
                              void* d_out, int out_size, void* d_ws, size_t ws_size,
                              hipStream_t stream) {
    const float* overts = (const float*)d_in[0];
    const int*   ofaces = (const int*)d_in[1];
    const float* sverts = (const float*)d_in[2];
    const int*   sfaces = (const int*)d_in[3];
    const float* fp     = (const float*)d_in[4];
    const float* u1     = (const float*)d_in[5];
    const float* u2     = (const float*)d_in[6];
    float* out = (float*)d_out;

    const int N_ORIG = in_sizes[0] / 3;
    const int F_ORIG = in_sizes[1] / 3;
    const int F_SIMP = in_sizes[3] / 3;
    const int S      = in_sizes[5] / F_SIMP;
    const int NPTS   = F_SIMP * S;

    // workspace: obc4 | overts4 | fwdPts | revPts | fwd_min | rev_min | acc
    float4* obc4    = (float4*)d_ws;
    float4* overts4 = obc4 + F_ORIG;
    float4* fwdPts  = overts4 + N_ORIG;
    float4* revPts  = fwdPts + F_SIMP;
    unsigned int* fwd_min = (unsigned int*)(revPts + NPTS);
    unsigned int* rev_min = fwd_min + F_SIMP;
    float* acc = (float*)(rev_min + NPTS);

    int prepN = max(max(NPTS, F_ORIG), N_ORIG);
    hipLaunchKernelGGL(prep_kernel, dim3((prepN + FBLK - 1) / FBLK), dim3(FBLK), 0, stream,
                       overts, ofaces, sverts, sfaces, u1, u2,
                       obc4, overts4, fwdPts, revPts, fwd_min, rev_min, acc,
                       N_ORIG, F_ORIG, F_SIMP, S, NPTS);

    // fwd: 1 point-block x 100 tiles = 100; rev: 8 point-blocks x 50 tiles = 400
    // -> 500 blocks x 16 waves = 8000 waves (vs 8192 slots)
    const int fwdPtBlocks = (F_SIMP + BLK * P - 1) / (BLK * P);
    const int fwdTiles    = (F_ORIG + TILE - 1) / TILE;
    const int fwdBlocks   = fwdPtBlocks * fwdTiles;

    const int revPtBlocks = (NPTS + BLK * P - 1) / (BLK * P);
    const int revTiles    = (N_ORIG + TILE - 1) / TILE;
    const int revBlocks   = revPtBlocks * revTiles;

    hipLaunchKernelGGL(min_kernel, dim3(fwdBlocks + revBlocks), dim3(BLK), 0, stream,
                       fwdPts, revPts, obc4, overts4, fwd_min, rev_min,
                       fwdBlocks, fwdPtBlocks, F_ORIG, F_SIMP,
                       revPtBlocks, N_ORIG, NPTS);

    const int finBlocks = (NPTS + FBLK - 1) / FBLK;
    hipLaunchKernelGGL(finalize_kernel, dim3(finBlocks), dim3(FBLK), 0, stream,
                       fwd_min, rev_min, fp, acc, out, F_SIMP, NPTS, S, finBlocks);
}